// Round 23
// baseline (191.140 us; speedup 1.0000x reference)
//
#include <hip/hip_runtime.h>
#include <stdint.h>

// ---------------------------------------------------------------------------
// Types
// ---------------------------------------------------------------------------
typedef __attribute__((ext_vector_type(8))) short bf16x8;   // 8 bf16 (4 VGPRs)
typedef __attribute__((ext_vector_type(8))) unsigned short u16x8;
typedef __attribute__((ext_vector_type(4))) float f32x4;    // 16x16 MFMA acc
typedef __attribute__((ext_vector_type(16))) float f32x16;  // 32x32 MFMA acc

__device__ __forceinline__ unsigned short f2b(float f) {
  union { float f; uint32_t u; } v; v.f = f;
  uint32_t u = v.u;
  return (unsigned short)((u + 0x7FFFu + ((u >> 16) & 1u)) >> 16);  // RNE
}

// async global->LDS, 16B per lane. lds_uniform = wave-uniform base; HW writes
// lane i at base + i*16. Global src is per-lane.
__device__ __forceinline__ void gll16(const unsigned short* gsrc, unsigned short* lds_uniform) {
  __builtin_amdgcn_global_load_lds(
      (const __attribute__((address_space(1))) uint32_t*)gsrc,
      (__attribute__((address_space(3))) uint32_t*)lds_uniform,
      16, 0, 0);
}

#define MFMA(a, b, c) __builtin_amdgcn_mfma_f32_16x16x32_bf16((a), (b), (c), 0, 0, 0)
#define MFMA32(a, b, c) __builtin_amdgcn_mfma_f32_32x32x16_bf16((a), (b), (c), 0, 0, 0)

// ---------------------------------------------------------------------------
// Merged cast kernel, 16B/lane global ops throughout. Linear grid 7169.
//  id < 4096 : x f32 [4][4096][1024] -> xb bf16 row-major AND xT bf16
//              [4][1024][4096] (transposed), 64x64 tiles, 8 elems/thread.
//  id >= 4096: weight casts (512 blocks each; Wq pre-scaled by log2e/8) +
//              EFbias concat (last slot, first block).
// ---------------------------------------------------------------------------
__global__ void cast_all(
    const float* __restrict__ x, unsigned short* __restrict__ xb,
    unsigned short* __restrict__ xT,
    const float* __restrict__ s0, const float* __restrict__ s1,
    const float* __restrict__ s2, const float* __restrict__ s3,
    const float* __restrict__ s4, const float* __restrict__ s5,
    const float* __restrict__ E_b, const float* __restrict__ F_b,
    unsigned short* __restrict__ d0, unsigned short* __restrict__ d1,
    unsigned short* __restrict__ d2, unsigned short* __restrict__ d3,
    unsigned short* __restrict__ d4, unsigned short* __restrict__ d5,
    float* __restrict__ EFbias) {
  __shared__ unsigned short tile[64][65];   // +1 pad: conflict-benign transpose
  const int id = blockIdx.x;
  const int t = threadIdx.x;

  if (id < 4096) {
    const int st = (id & 63) * 64;
    const int ct = ((id >> 6) & 15) * 64;
    const int b = id >> 10;
#pragma unroll
    for (int it = 0; it < 2; ++it) {
      int linear = (it * 256 + t) * 8;
      int r = linear >> 6, c = linear & 63;   // r = s idx, c = c idx (mult of 8)
      const float* src = x + ((size_t)(b * 4096 + st + r)) * 1024 + ct + c;
      float4 v0 = *(const float4*)(src);
      float4 v1 = *(const float4*)(src + 4);
      u16x8 o;
      o[0] = f2b(v0.x); o[1] = f2b(v0.y); o[2] = f2b(v0.z); o[3] = f2b(v0.w);
      o[4] = f2b(v1.x); o[5] = f2b(v1.y); o[6] = f2b(v1.z); o[7] = f2b(v1.w);
      *(u16x8*)(xb + ((size_t)(b * 4096 + st + r)) * 1024 + ct + c) = o;
#pragma unroll
      for (int j = 0; j < 8; ++j) tile[r][c + j] = o[j];
    }
    __syncthreads();
#pragma unroll
    for (int it = 0; it < 2; ++it) {
      int linear = (it * 256 + t) * 8;
      int r = linear >> 6, c = linear & 63;   // r = c idx, c = s idx (mult of 8)
      u16x8 o;
#pragma unroll
      for (int j = 0; j < 8; ++j) o[j] = tile[c + j][r];
      *(u16x8*)(xT + ((size_t)b * 1024 + ct + r) * 4096 + st + c) = o;
    }
    return;
  }

  // ---- weight casts: id2 = id-4096; cy = id2>>9 (0..6), cx = id2&511 ----
  const int id2 = id - 4096;
  const int cx = id2 & 511, cy = id2 >> 9;
  if (cy == 6) {
    if (cx == 0) {
      EFbias[t] = E_b[t];
      EFbias[256 + t] = F_b[t];
    }
    return;
  }
  const float* src; unsigned short* dst; float sc = 1.0f;
  switch (cy) {
    case 0: src = s0; dst = d0; sc = 0.18033688011112042f; break;
    case 1: src = s1; dst = d1; break;
    case 2: src = s2; dst = d2; break;
    case 3: src = s3; dst = d3; break;
    case 4: src = s4; dst = d4; break;
    default: src = s5; dst = d5; break;
  }
  int i = (cx * 256 + t) * 8;
  float4 v0 = *(const float4*)(src + i);
  float4 v1 = *(const float4*)(src + i + 4);
  u16x8 o;
  o[0] = f2b(v0.x * sc); o[1] = f2b(v0.y * sc); o[2] = f2b(v0.z * sc); o[3] = f2b(v0.w * sc);
  o[4] = f2b(v1.x * sc); o[5] = f2b(v1.y * sc); o[6] = f2b(v1.z * sc); o[7] = f2b(v1.w * sc);
  *(u16x8*)(dst + i) = o;
}

// ---------------------------------------------------------------------------
// 256x256-tile BT GEMM, BK=32, 1024 threads = 16 waves (4M x 4N), each wave
// owns 64x64. 4-buffer counted-vmcnt ring, 3-tile lookahead (R19-proven):
// wave stages 1 A-chunk + 1 B-chunk per tile; closing vmcnt(4) retires tile
// t+1 (FIFO: t+2,t+3's loads stay in flight). Ladder 4/2/0.
// ---------------------------------------------------------------------------
template <int BIAS, bool OBF16>
__global__ __launch_bounds__(1024) void gemm_bt256(
    const unsigned short* __restrict__ A, const unsigned short* __restrict__ B,
    void* __restrict__ Cout, const float* __restrict__ bias,
    int K, int lda, int ldb, int ldc) {
  __shared__ unsigned short Asm_[4][256 * 32];
  __shared__ unsigned short Bsm_[4][256 * 32];
  const int tid = threadIdx.x;
  const int wave = tid >> 6, lane = tid & 63;
  const int g = (lane >> 4) & 3, l15 = lane & 15;
  const int wmi = wave >> 2, wni = wave & 3;        // wave grid 4M x 4N
  const int bm = blockIdx.x * 256, bn = blockIdx.y * 256;

  const int rr = wave * 16 + (lane >> 2);           // tile row 0..255
  const int sl = (lane & 3) ^ ((rr >> 1) & 3);      // pre-swizzled source slot

#define STG(T, BUF)                                                              \
  {                                                                              \
    int kt_ = (T) * 32;                                                          \
    gll16(A + (size_t)(bm + rr) * lda + kt_ + sl * 8, Asm_[BUF] + wave * 512);   \
    gll16(B + (size_t)(bn + rr) * ldb + kt_ + sl * 8, Bsm_[BUF] + wave * 512);   \
  }

  f32x4 acc[4][4];
#pragma unroll
  for (int i = 0; i < 4; ++i)
#pragma unroll
    for (int j = 0; j < 4; ++j) acc[i][j] = (f32x4){0.f, 0.f, 0.f, 0.f};

  const int nt = K >> 5;
  STG(0, 0);
  if (nt > 1) STG(1, 1);
  if (nt > 2) STG(2, 2);
  asm volatile("s_waitcnt vmcnt(4)" ::: "memory");   // tile0 landed; t1,t2 in flight
  __builtin_amdgcn_s_barrier();
  asm volatile("" ::: "memory");

  for (int t = 0; t < nt; ++t) {
    const int cur = t & 3;
    const char* Ac = (const char*)Asm_[cur];
    const char* Bc = (const char*)Bsm_[cur];

    bf16x8 afr[4], bfr[4];
#pragma unroll
    for (int mf = 0; mf < 4; ++mf) {
      int m = wmi * 64 + mf * 16 + l15;
      afr[mf] = *(const bf16x8*)(Ac + m * 64 + ((g ^ ((m >> 1) & 3)) << 4));
    }
#pragma unroll
    for (int nf = 0; nf < 4; ++nf) {
      int n = wni * 64 + nf * 16 + l15;
      bfr[nf] = *(const bf16x8*)(Bc + n * 64 + ((g ^ ((n >> 1) & 3)) << 4));
    }

    if (t + 3 < nt) STG(t + 3, (t + 3) & 3);

    __builtin_amdgcn_s_setprio(1);
#pragma unroll
    for (int mf = 0; mf < 4; ++mf)
#pragma unroll
      for (int nf = 0; nf < 4; ++nf)
        acc[mf][nf] = MFMA(afr[mf], bfr[nf], acc[mf][nf]);
    __builtin_amdgcn_s_setprio(0);

    if (t + 3 < nt)      asm volatile("s_waitcnt vmcnt(4)" ::: "memory");
    else if (t + 2 < nt) asm volatile("s_waitcnt vmcnt(2)" ::: "memory");
    else                 asm volatile("s_waitcnt vmcnt(0)" ::: "memory");
    __builtin_amdgcn_s_barrier();
    asm volatile("" ::: "memory");
  }
#undef STG

#pragma unroll
  for (int mf = 0; mf < 4; ++mf)
#pragma unroll
    for (int r = 0; r < 4; ++r) {
      int row = bm + wmi * 64 + mf * 16 + g * 4 + r;
      float rb = (BIAS == 1) ? bias[row] : 0.f;
#pragma unroll
      for (int nf = 0; nf < 4; ++nf) {
        int col = bn + wni * 64 + nf * 16 + l15;
        float v = acc[mf][nf][r] + rb + ((BIAS == 2) ? bias[col] : 0.f);
        if (OBF16) ((unsigned short*)Cout)[(size_t)row * ldc + col] = f2b(v);
        else       ((float*)Cout)[(size_t)row * ldc + col] = v;
      }
    }
}

// ---------------------------------------------------------------------------
// xEF split-K GEMM, 128x128 tile, 3-buffer counted pipeline, split=2
// (K=2048 per slice): Cpart[z][512][1024] f32, z = split*4 + b, 8 z-slices.
// ---------------------------------------------------------------------------
__global__ __launch_bounds__(256, 2) void gemm_xef_splitk(
    const unsigned short* __restrict__ A,
    const unsigned short* __restrict__ B,
    float* __restrict__ Cpart) {
  __shared__ unsigned short Asm_[3][128 * 32];
  __shared__ unsigned short Bsm_[3][128 * 32];
  const int tid = threadIdx.x;
  const int wave = tid >> 6, lane = tid & 63;
  const int g = lane >> 4, l15 = lane & 15;
  const int bm = blockIdx.x * 128, bn = blockIdx.y * 128;
  const int z = blockIdx.z, split = z >> 2, b = z & 3;
  const unsigned short* Ab = A + split * 2048;                    // K-offset
  const unsigned short* Bb = B + (size_t)b * 1024 * 4096 + split * 2048;
  const int wm = (wave >> 1) * 64, wn = (wave & 1) * 64;

  const int rr0 = wave * 16 + (lane >> 2);
  const int rr1 = rr0 + 64;
  const int sl0 = (lane & 3) ^ ((rr0 >> 1) & 3);
  const int sl1 = (lane & 3) ^ ((rr1 >> 1) & 3);

#define XEF_STAGE(T, BUF)                                                           \
  {                                                                                 \
    int kt_ = (T) * 32;                                                             \
    gll16(Ab + (size_t)(bm + rr0) * 4096 + kt_ + sl0 * 8, Asm_[BUF] + wave * 512);  \
    gll16(Bb + (size_t)(bn + rr0) * 4096 + kt_ + sl0 * 8, Bsm_[BUF] + wave * 512);  \
    gll16(Ab + (size_t)(bm + rr1) * 4096 + kt_ + sl1 * 8, Asm_[BUF] + (wave + 4) * 512); \
    gll16(Bb + (size_t)(bn + rr1) * 4096 + kt_ + sl1 * 8, Bsm_[BUF] + (wave + 4) * 512); \
  }

  f32x4 acc[4][4];
#pragma unroll
  for (int i = 0; i < 4; ++i)
#pragma unroll
    for (int j = 0; j < 4; ++j) acc[i][j] = (f32x4){0.f, 0.f, 0.f, 0.f};

  const int nt = 64;
  XEF_STAGE(0, 0);
  XEF_STAGE(1, 1);
  asm volatile("s_waitcnt vmcnt(4)" ::: "memory");   // tile0 landed; tile1 in flight
  __builtin_amdgcn_s_barrier();
  asm volatile("" ::: "memory");

  for (int t = 0; t < nt; ++t) {
    const int cur = t % 3;
    const char* Ac = (const char*)Asm_[cur];
    const char* Bc = (const char*)Bsm_[cur];

    bf16x8 af[4], bfr[4];
#pragma unroll
    for (int mi = 0; mi < 4; ++mi) {
      int m = wm + mi * 16 + l15;
      af[mi] = *(const bf16x8*)(Ac + m * 64 + ((g ^ ((m >> 1) & 3)) << 4));
    }
#pragma unroll
    for (int ni = 0; ni < 4; ++ni) {
      int n = wn + ni * 16 + l15;
      bfr[ni] = *(const bf16x8*)(Bc + n * 64 + ((g ^ ((n >> 1) & 3)) << 4));
    }

    if (t + 2 < nt) XEF_STAGE(t + 2, (t + 2) % 3);

#pragma unroll
    for (int mi = 0; mi < 4; ++mi)
#pragma unroll
      for (int ni = 0; ni < 4; ++ni)
        acc[mi][ni] = MFMA(af[mi], bfr[ni], acc[mi][ni]);

    // retire tile t+1's 4 stages (every wave); keep t+2's 4 in flight
    if (t + 2 < nt) asm volatile("s_waitcnt vmcnt(4)" ::: "memory");
    else            asm volatile("s_waitcnt vmcnt(0)" ::: "memory");
    __builtin_amdgcn_s_barrier();
    asm volatile("" ::: "memory");
  }
#undef XEF_STAGE

  float* C = Cpart + (size_t)z * (512 * 1024);
#pragma unroll
  for (int mi = 0; mi < 4; ++mi)
#pragma unroll
    for (int r = 0; r < 4; ++r) {
      int row = bm + wm + mi * 16 + g * 4 + r;
#pragma unroll
      for (int ni = 0; ni < 4; ++ni) {
        int col = bn + wn + ni * 16 + l15;
        C[(size_t)row * 1024 + col] = acc[mi][ni][r];
      }
    }
}

// ---------------------------------------------------------------------------
// Reduce 2 split-K partials -> xEF bf16 [4][512][1024], + EF bias (per row).
// Split-1 partials at float offset 4*512*1024 = 2,097,152. 8 floats/thread.
// ---------------------------------------------------------------------------
__global__ void reduce_xef(const float* __restrict__ P,
                           const float* __restrict__ bias,
                           unsigned short* __restrict__ out) {
  int t = blockIdx.x * 256 + threadIdx.x;     // 0..262143
  size_t flat = (size_t)t * 8;                // over [4][512][1024]
  float4 a0 = *(const float4*)(P + flat);
  float4 a1 = *(const float4*)(P + flat + 4);
  float4 b0 = *(const float4*)(P + (size_t)2097152 + flat);
  float4 b1 = *(const float4*)(P + (size_t)2097152 + flat + 4);
  float rb = bias[(flat >> 10) & 511];
  u16x8 o;
  o[0] = f2b(a0.x + b0.x + rb); o[1] = f2b(a0.y + b0.y + rb);
  o[2] = f2b(a0.z + b0.z + rb); o[3] = f2b(a0.w + b0.w + rb);
  o[4] = f2b(a1.x + b1.x + rb); o[5] = f2b(a1.y + b1.y + rb);
  o[6] = f2b(a1.z + b1.z + rb); o[7] = f2b(a1.w + b1.w + rb);
  *(u16x8*)(out + flat) = o;
}

// ---------------------------------------------------------------------------
// Merged Kp+Vp GEMM: 512 linear blocks of 256 threads, 64x64 tiles, BK=32,
// 3-buffer counted pipeline (R18-proven body). id<256 = Kp job
// (Kp[b][16][256][64] = xE[b]*Wk^T, head-blocked epilogue); else Vp job
// (Vp[b][hd][dk-permuted] = Wv*xF[b]^T, k-bit-swap epilogue). K=1024 both.
// ---------------------------------------------------------------------------
__global__ __launch_bounds__(256, 4) void gemm_kpvp(
    const unsigned short* __restrict__ xEF, const unsigned short* __restrict__ Wkb,
    const unsigned short* __restrict__ Wvb, unsigned short* __restrict__ Kp,
    unsigned short* __restrict__ Vp) {
  __shared__ unsigned short Asm_[3][64 * 32];
  __shared__ unsigned short Bsm_[3][64 * 32];
  const int tid = threadIdx.x;
  const int wave = tid >> 6, lane = tid & 63;
  const int g = lane >> 4, l15 = lane & 15;

  const int id = blockIdx.x;
  const bool isV = id >= 256;
  const int id2 = isV ? id - 256 : id;
  int bm, bn, bz;
  const unsigned short *Ab, *Bb;
  if (!isV) {                       // Kp: grid was (4,16,4)
    bm = (id2 & 3) * 64; bn = ((id2 >> 2) & 15) * 64; bz = id2 >> 6;
    Ab = xEF + (size_t)bz * (512 * 1024);            // xE rows 0..255
    Bb = Wkb;
  } else {                          // Vp: grid was (16,4,4)
    bm = (id2 & 15) * 64; bn = ((id2 >> 4) & 3) * 64; bz = id2 >> 6;
    Ab = Wvb;
    Bb = xEF + (size_t)bz * (512 * 1024) + 256 * 1024;  // xF rows
  }
  const int wm = (wave >> 1) * 32, wn = (wave & 1) * 32;

  const int rr = wave * 16 + (lane >> 2);
  const int sl = (lane & 3) ^ ((rr >> 1) & 3);

#define KV_STAGE(T, BUF)                                                         \
  {                                                                              \
    int kt_ = (T) * 32;                                                          \
    gll16(Ab + (size_t)(bm + rr) * 1024 + kt_ + sl * 8, Asm_[BUF] + wave * 512); \
    gll16(Bb + (size_t)(bn + rr) * 1024 + kt_ + sl * 8, Bsm_[BUF] + wave * 512); \
  }

  f32x4 acc[2][2];
#pragma unroll
  for (int i = 0; i < 2; ++i)
#pragma unroll
    for (int j = 0; j < 2; ++j) acc[i][j] = (f32x4){0.f, 0.f, 0.f, 0.f};

  const int nt = 32;                 // K = 1024
  KV_STAGE(0, 0);
  KV_STAGE(1, 1);
  asm volatile("s_waitcnt vmcnt(2)" ::: "memory");   // tile0 landed; tile1 in flight
  __builtin_amdgcn_s_barrier();
  asm volatile("" ::: "memory");

  for (int t = 0; t < nt; ++t) {
    const int cur = t % 3;
    const char* Ac = (const char*)Asm_[cur];
    const char* Bc = (const char*)Bsm_[cur];

    bf16x8 af[2], bfr[2];
#pragma unroll
    for (int mi = 0; mi < 2; ++mi) {
      int m = wm + mi * 16 + l15;
      af[mi] = *(const bf16x8*)(Ac + m * 64 + ((g ^ ((m >> 1) & 3)) << 4));
    }
#pragma unroll
    for (int ni = 0; ni < 2; ++ni) {
      int n = wn + ni * 16 + l15;
      bfr[ni] = *(const bf16x8*)(Bc + n * 64 + ((g ^ ((n >> 1) & 3)) << 4));
    }

    if (t + 2 < nt) KV_STAGE(t + 2, (t + 2) % 3);

#pragma unroll
    for (int mi = 0; mi < 2; ++mi)
#pragma unroll
      for (int ni = 0; ni < 2; ++ni)
        acc[mi][ni] = MFMA(af[mi], bfr[ni], acc[mi][ni]);

    if (t + 2 < nt) asm volatile("s_waitcnt vmcnt(2)" ::: "memory");
    else            asm volatile("s_waitcnt vmcnt(0)" ::: "memory");
    __builtin_amdgcn_s_barrier();
    asm volatile("" ::: "memory");
  }
#undef KV_STAGE

#pragma unroll
  for (int mi = 0; mi < 2; ++mi)
#pragma unroll
    for (int r = 0; r < 4; ++r) {
      int row = bm + wm + mi * 16 + g * 4 + r;
#pragma unroll
      for (int ni = 0; ni < 2; ++ni) {
        int col = bn + wn + ni * 16 + l15;
        float v = acc[mi][ni][r];
        if (!isV) {
          // head-blocked: Kp[bz] + (col>>6)*(256*64) + row*64 + (col&63)
          unsigned short* C = Kp + (size_t)bz * (256 * 1024);
          C[(size_t)(col >> 6) * 16384 + (size_t)row * 64 + (col & 63)] = f2b(v);
        } else {
          // row-major ldc=256, low-4 col bits permuted (swap bits 2<->3)
          unsigned short* C = Vp + (size_t)bz * (1024 * 256);
          int cl = col & 15;
          int cp = (cl & 3) | ((cl & 4) << 1) | ((cl & 8) >> 1);
          C[(size_t)row * 256 + (col & ~15) + cp] = f2b(v);
        }
      }
    }
}

// ---------------------------------------------------------------------------
// Fused attention v10 per (b, h, 256-row s-block); 8 waves x 32 rows each.
// V staged in LDS once per block (32KB, XOR-swizzled); MFMA row-sum
// denominator; P fully register-resident. (R16-proven, unchanged.)
// ---------------------------------------------------------------------------
__global__ __launch_bounds__(512, 2) void attn_kernel(
    const unsigned short* __restrict__ q,     // [16384, 1024] (Wq pre-scaled)
    const unsigned short* __restrict__ kp,    // [4][16][256][64]
    const unsigned short* __restrict__ vp,    // [4][16][64][256] k-permuted
    unsigned short* __restrict__ ho) {        // [16384, 1024]
  __shared__ unsigned short Ksm[256 * 64];    // [k][d] 128B rows, swizzled
  __shared__ unsigned short Vsm[64 * 256];    // [d][k] 512B rows, slot^(row&7)

  const int tid = threadIdx.x;
  const int wave = tid >> 6, lane = tid & 63;
  const int l31 = lane & 31, hi = lane >> 5;
  const int x = blockIdx.x;                   // 1024 blocks
  const int bh = (x & 7) + ((x >> 7) << 3);   // head id 0..63 (XCD-local)
  const int qq = (x >> 3) & 15;               // s-block 0..15
  const int b = bh >> 4, h = bh & 15;
  const int s0 = qq * 256;

  const unsigned short* kph = kp + (size_t)bh * (256 * 64);
  const unsigned short* vph = vp + (size_t)bh * (64 * 256);

  // stage K [256][64]: 32 chunks of 1KB over 8 waves. chunk c: rows c*8..+7.
  {
    const int r = (lane >> 3), sl = (lane & 7) ^ (lane >> 3);
#pragma unroll
    for (int it = 0; it < 4; ++it) {
      int c = it * 8 + wave;
      gll16(kph + (c * 8 + r) * 64 + sl * 8, Ksm + c * 512);
    }
  }
  // stage V [64][256]: 32 chunks of 1KB (2 rows each) over 8 waves.
  {
    const int rv = lane >> 5;                 // row within chunk
#pragma unroll
    for (int it = 0; it < 4; ++it) {
      int c = it * 8 + wave;
      int row = c * 2 + rv;
      int sl = (lane & 31) ^ (row & 7);
      gll16(vph + (size_t)row * 256 + sl * 8, Vsm + c * 512);
    }
  }

  // Q B-fragments (persistent): lane l31 = s-col, slots = d = dc*16+hi*8+i
  const int srow = s0 + wave * 32 + l31;
  const unsigned short* qrow = q + (size_t)(b * 4096 + srow) * 1024 + h * 64;
  bf16x8 qf[4];
#pragma unroll
  for (int dc = 0; dc < 4; ++dc)
    qf[dc] = *(const bf16x8*)(qrow + dc * 16 + hi * 8);

  bf16x8 ones;
#pragma unroll
  for (int j = 0; j < 8; ++j) ones[j] = (short)0x3F80;   // bf16 1.0

  __syncthreads();   // drains K+V staging

  f32x16 ho0 = {0,0,0,0,0,0,0,0,0,0,0,0,0,0,0,0};
  f32x16 ho1 = {0,0,0,0,0,0,0,0,0,0,0,0,0,0,0,0};
  f32x16 sumacc = {0,0,0,0,0,0,0,0,0,0,0,0,0,0,0,0};

  const int vsw0 = l31 & 7;                   // row swizzle for rows l31, 32+l31
#pragma unroll
  for (int t = 0; t < 8; ++t) {
    bf16x8 vf00 = *(const bf16x8*)((const char*)Vsm + l31 * 512 + (((t * 4 + hi) ^ vsw0) << 4));
    bf16x8 vf01 = *(const bf16x8*)((const char*)Vsm + l31 * 512 + (((t * 4 + 2 + hi) ^ vsw0) << 4));
    bf16x8 vf10 = *(const bf16x8*)((const char*)Vsm + (32 + l31) * 512 + (((t * 4 + hi) ^ vsw0) << 4));
    bf16x8 vf11 = *(const bf16x8*)((const char*)Vsm + (32 + l31) * 512 + (((t * 4 + 2 + hi) ^ vsw0) << 4));

    // QK^T: C[k=32 rows][s=32 cols], contraction d=64 in 4 chunks
    f32x16 qk = {0,0,0,0,0,0,0,0,0,0,0,0,0,0,0,0};
    const int krow = t * 32 + l31;
    const char* kbase = (const char*)Ksm + krow * 128;
#pragma unroll
    for (int dc = 0; dc < 4; ++dc) {
      bf16x8 kf = *(const bf16x8*)(kbase + (((dc * 2 + hi) ^ (l31 & 7)) << 4));
      qk = MFMA32(kf, qf[dc], qk);
    }

    // exp2 (scale baked into Wq) + pack to PV A-frags (no scalar sum)
    uint32_t pk[8];
#pragma unroll
    for (int j = 0; j < 8; ++j) {
      float e0 = exp2f(qk[2 * j]);
      float e1 = exp2f(qk[2 * j + 1]);
      asm("v_cvt_pk_bf16_f32 %0, %1, %2" : "=v"(pk[j]) : "v"(e0), "v"(e1));
    }
    union { uint32_t u[4]; bf16x8 v; } ua, ub;
    ua.u[0] = pk[0]; ua.u[1] = pk[1]; ua.u[2] = pk[2]; ua.u[3] = pk[3];
    ub.u[0] = pk[4]; ub.u[1] = pk[5]; ub.u[2] = pk[6]; ub.u[3] = pk[7];

    ho0 = MFMA32(ua.v, vf00, ho0);
    ho0 = MFMA32(ub.v, vf01, ho0);
    ho1 = MFMA32(ua.v, vf10, ho1);
    ho1 = MFMA32(ub.v, vf11, ho1);
    // denominator: row-sum of P via ones-B MFMA; same C-row layout as ho
    sumacc = MFMA32(ua.v, ones, sumacc);
    sumacc = MFMA32(ub.v, ones, sumacc);
  }

  float rl[16];
#pragma unroll
  for (int reg = 0; reg < 16; ++reg)
    rl[reg] = __builtin_amdgcn_rcpf(sumacc[reg]);

  unsigned short* hob = ho + (size_t)(b * 4096 + s0 + wave * 32) * 1024 + h * 64 + l31;
#pragma unroll
  for (int reg = 0; reg < 16; ++reg) {
    int srw = (reg & 3) + 8 * (reg >> 2) + 4 * hi;
    hob[(size_t)srw * 1024]      = f2b(ho0[reg] * rl[reg]);
    hob[(size_t)srw * 1024 + 32] = f2b(ho1[reg] * rl[reg]);
  }
}

// ---------------------------------------------------------------------------
// Host orchestration
// ---------------------------------------------------------------------------
extern "C" void kernel_launch(void* const* d_in, const int* in_sizes, int n_in,
                              void* d_out, int out_size, void* d_ws, size_t ws_size,
                              hipStream_t stream) {
  (void)in_sizes; (void)n_in; (void)out_size; (void)ws_size;
  const float* x   = (const float*)d_in[0];
  const float* Wq  = (const float*)d_in[1];
  const float* Wk  = (const float*)d_in[2];
  const float* Wv  = (const float*)d_in[3];
  const float* E_w = (const float*)d_in[4];
  const float* E_b = (const float*)d_in[5];
  const float* F_w = (const float*)d_in[6];
  const float* F_b = (const float*)d_in[7];
  const float* Wo  = (const float*)d_in[8];
  const float* bo  = (const float*)d_in[9];
  float* out = (float*)d_out;

  char* ws = (char*)d_ws;
  unsigned short* xb   = (unsigned short*)(ws);               // 33,554,432 (reused as HO)
  unsigned short* xT   = (unsigned short*)(ws + 33554432);    // 33,554,432  [4][1024][4096]
  unsigned short* Qb   = (unsigned short*)(ws + 67108864);    // 33,554,432  [16384][1024]
  unsigned short* Wqb  = (unsigned short*)(ws + 100663296);   //  2,097,152
  unsigned short* Wkb  = (unsigned short*)(ws + 102760448);   //  2,097,152
  unsigned short* Wvb  = (unsigned short*)(ws + 104857600);   //  2,097,152
  unsigned short* Wob  = (unsigned short*)(ws + 106954752);   //  2,097,152
  unsigned short* EFb  = (unsigned short*)(ws + 109051904);   //  4,194,304  [512][4096]
  unsigned short* xEF  = (unsigned short*)(ws + 113246208);   //  4,194,304  [4][512][1024]
  unsigned short* Kp   = (unsigned short*)(ws + 117440512);   //  2,097,152  [4][16][256][64]
  unsigned short* Vp   = (unsigned short*)(ws + 119537664);   //  2,097,152  [4][16][64][256] perm
  float*          EFbias = (float*)(ws + 121634816);          //  2,048      [512]
  float*          Ppart  = (float*)(ws + 121700352);          // 16,777,216  [2][4][512][1024] f32
  unsigned short* HO   = xb;   // xb dead after Q-GEMM

  // merged casts: x -> xb + xT (blocks 0..4095); weights + EFbias (4096..7168)
  cast_all<<<dim3(7169), 256, 0, stream>>>(
      x, xb, xT,
      Wq, Wk, Wv, E_w, F_w, Wo, E_b, F_b,
      Wqb, Wkb, Wvb, EFb, EFb + 2097152 / 2, Wob, EFbias);

  // Q = xb * Wq^T   [16384,1024]   (Wq pre-scaled by log2e/8), 256^2 tiles
  gemm_bt256<0, true><<<dim3(64, 4), 1024, 0, stream>>>(
      xb, Wqb, Qb, nullptr, 1024, 1024, 1024, 1024);

  // xEF split-K (2 slices of K=2048): Ppart[z] = EF * xT[b]^T, z = split*4+b
  gemm_xef_splitk<<<dim3(4, 8, 8), 256, 0, stream>>>(EFb, xT, Ppart);
  // reduce partials + bias -> xEF bf16 [4][512][1024]
  reduce_xef<<<dim3(1024, 1, 1), 256, 0, stream>>>(Ppart, EFbias, xEF);

  // merged Kp + Vp GEMMs (512 linear blocks)
  gemm_kpvp<<<dim3(512), 256, 0, stream>>>(xEF, Wkb, Wvb, Kp, Vp);

  // fused attention -> HO [16384,1024]  (8-wave blocks, 256 rows each)
  attn_kernel<<<dim3(1024, 1, 1), 512, 0, stream>>>(Qb, Kp, Vp, HO);

  // out = HO * Wo^T + bo   (f32), 256^2 tiles, 1024 threads (16 waves)
  gemm_bt256<2, false><<<dim3(64, 4), 1024, 0, stream>>>(
      HO, Wob, out, bo, 1024, 1024, 1024, 1024);
}

// Round 24
// 190.116 us; speedup vs baseline: 1.0054x; 1.0054x over previous
//
#include <hip/hip_runtime.h>
#include <stdint.h>

// ---------------------------------------------------------------------------
// Types
// ---------------------------------------------------------------------------
typedef __attribute__((ext_vector_type(8))) short bf16x8;   // 8 bf16 (4 VGPRs)
typedef __attribute__((ext_vector_type(8))) unsigned short u16x8;
typedef __attribute__((ext_vector_type(4))) float f32x4;    // 16x16 MFMA acc
typedef __attribute__((ext_vector_type(16))) float f32x16;  // 32x32 MFMA acc

__device__ __forceinline__ unsigned short f2b(float f) {
  union { float f; uint32_t u; } v; v.f = f;
  uint32_t u = v.u;
  return (unsigned short)((u + 0x7FFFu + ((u >> 16) & 1u)) >> 16);  // RNE
}

// async global->LDS, 16B per lane. lds_uniform = wave-uniform base; HW writes
// lane i at base + i*16. Global src is per-lane.
__device__ __forceinline__ void gll16(const unsigned short* gsrc, unsigned short* lds_uniform) {
  __builtin_amdgcn_global_load_lds(
      (const __attribute__((address_space(1))) uint32_t*)gsrc,
      (__attribute__((address_space(3))) uint32_t*)lds_uniform,
      16, 0, 0);
}

#define MFMA(a, b, c) __builtin_amdgcn_mfma_f32_16x16x32_bf16((a), (b), (c), 0, 0, 0)
#define MFMA32(a, b, c) __builtin_amdgcn_mfma_f32_32x32x16_bf16((a), (b), (c), 0, 0, 0)

// ---------------------------------------------------------------------------
// Merged cast kernel. Linear grid 4097.
//  id < 1024 : x f32 [4][4096][1024] -> xb bf16 row-major AND xT bf16
//              [4][1024][4096], 128x128 tiles so每 row write is 256B
//              contiguous for BOTH outputs. LDS pitch 130 (2-way max).
//  id >= 1024: weight casts (512 blocks each; Wq pre-scaled by log2e/8) +
//              EFbias concat (last block).
// ---------------------------------------------------------------------------
__global__ void cast_all(
    const float* __restrict__ x, unsigned short* __restrict__ xb,
    unsigned short* __restrict__ xT,
    const float* __restrict__ s0, const float* __restrict__ s1,
    const float* __restrict__ s2, const float* __restrict__ s3,
    const float* __restrict__ s4, const float* __restrict__ s5,
    const float* __restrict__ E_b, const float* __restrict__ F_b,
    unsigned short* __restrict__ d0, unsigned short* __restrict__ d1,
    unsigned short* __restrict__ d2, unsigned short* __restrict__ d3,
    unsigned short* __restrict__ d4, unsigned short* __restrict__ d5,
    float* __restrict__ EFbias) {
  __shared__ unsigned short tile[128 * 130];   // pitch 130: gather 2-way max
  const int id = blockIdx.x;
  const int t = threadIdx.x;

  if (id < 1024) {
    const int st = (id & 31) * 128;            // s tile (32)
    const int ct = ((id >> 5) & 7) * 128;      // c tile (8)
    const int b = id >> 8;                     // batch (4)
#pragma unroll
    for (int it = 0; it < 8; ++it) {
      int linear = (it * 256 + t) * 8;
      int r = linear >> 7, c = linear & 127;   // r = s idx, c = c idx (mult 8)
      const float* src = x + ((size_t)(b * 4096 + st + r)) * 1024 + ct + c;
      float4 v0 = *(const float4*)(src);
      float4 v1 = *(const float4*)(src + 4);
      u16x8 o;
      o[0] = f2b(v0.x); o[1] = f2b(v0.y); o[2] = f2b(v0.z); o[3] = f2b(v0.w);
      o[4] = f2b(v1.x); o[5] = f2b(v1.y); o[6] = f2b(v1.z); o[7] = f2b(v1.w);
      *(u16x8*)(xb + ((size_t)(b * 4096 + st + r)) * 1024 + ct + c) = o;
#pragma unroll
      for (int j = 0; j < 8; ++j) tile[r * 130 + c + j] = o[j];
    }
    __syncthreads();
#pragma unroll
    for (int it = 0; it < 8; ++it) {
      int linear = (it * 256 + t) * 8;
      int cr = linear >> 7, sc = linear & 127; // cr = c idx, sc = s idx (mult 8)
      u16x8 o;
#pragma unroll
      for (int j = 0; j < 8; ++j) o[j] = tile[(sc + j) * 130 + cr];
      *(u16x8*)(xT + ((size_t)b * 1024 + ct + cr) * 4096 + st + sc) = o;
    }
    return;
  }

  // ---- weight casts: id2 = id-1024; cy = id2>>9 (0..6), cx = id2&511 ----
  const int id2 = id - 1024;
  const int cx = id2 & 511, cy = id2 >> 9;
  if (cy == 6) {
    if (cx == 0) {
      EFbias[t] = E_b[t];
      EFbias[256 + t] = F_b[t];
    }
    return;
  }
  const float* src; unsigned short* dst; float sc = 1.0f;
  switch (cy) {
    case 0: src = s0; dst = d0; sc = 0.18033688011112042f; break;
    case 1: src = s1; dst = d1; break;
    case 2: src = s2; dst = d2; break;
    case 3: src = s3; dst = d3; break;
    case 4: src = s4; dst = d4; break;
    default: src = s5; dst = d5; break;
  }
  int i = (cx * 256 + t) * 8;
  float4 v0 = *(const float4*)(src + i);
  float4 v1 = *(const float4*)(src + i + 4);
  u16x8 o;
  o[0] = f2b(v0.x * sc); o[1] = f2b(v0.y * sc); o[2] = f2b(v0.z * sc); o[3] = f2b(v0.w * sc);
  o[4] = f2b(v1.x * sc); o[5] = f2b(v1.y * sc); o[6] = f2b(v1.z * sc); o[7] = f2b(v1.w * sc);
  *(u16x8*)(dst + i) = o;
}

// ---------------------------------------------------------------------------
// 256x256-tile BT GEMM, BK=32, 1024 threads = 16 waves (4M x 4N), each wave
// owns 64x64. 4-buffer counted-vmcnt ring, 3-tile lookahead (R19-proven):
// wave stages 1 A-chunk + 1 B-chunk per tile; closing vmcnt(4) retires tile
// t+1 (FIFO: t+2,t+3's loads stay in flight). Ladder 4/2/0.
// ---------------------------------------------------------------------------
template <int BIAS, bool OBF16>
__global__ __launch_bounds__(1024) void gemm_bt256(
    const unsigned short* __restrict__ A, const unsigned short* __restrict__ B,
    void* __restrict__ Cout, const float* __restrict__ bias,
    int K, int lda, int ldb, int ldc) {
  __shared__ unsigned short Asm_[4][256 * 32];
  __shared__ unsigned short Bsm_[4][256 * 32];
  const int tid = threadIdx.x;
  const int wave = tid >> 6, lane = tid & 63;
  const int g = (lane >> 4) & 3, l15 = lane & 15;
  const int wmi = wave >> 2, wni = wave & 3;        // wave grid 4M x 4N
  const int bm = blockIdx.x * 256, bn = blockIdx.y * 256;

  const int rr = wave * 16 + (lane >> 2);           // tile row 0..255
  const int sl = (lane & 3) ^ ((rr >> 1) & 3);      // pre-swizzled source slot

#define STG(T, BUF)                                                              \
  {                                                                              \
    int kt_ = (T) * 32;                                                          \
    gll16(A + (size_t)(bm + rr) * lda + kt_ + sl * 8, Asm_[BUF] + wave * 512);   \
    gll16(B + (size_t)(bn + rr) * ldb + kt_ + sl * 8, Bsm_[BUF] + wave * 512);   \
  }

  f32x4 acc[4][4];
#pragma unroll
  for (int i = 0; i < 4; ++i)
#pragma unroll
    for (int j = 0; j < 4; ++j) acc[i][j] = (f32x4){0.f, 0.f, 0.f, 0.f};

  const int nt = K >> 5;
  STG(0, 0);
  if (nt > 1) STG(1, 1);
  if (nt > 2) STG(2, 2);
  asm volatile("s_waitcnt vmcnt(4)" ::: "memory");   // tile0 landed; t1,t2 in flight
  __builtin_amdgcn_s_barrier();
  asm volatile("" ::: "memory");

  for (int t = 0; t < nt; ++t) {
    const int cur = t & 3;
    const char* Ac = (const char*)Asm_[cur];
    const char* Bc = (const char*)Bsm_[cur];

    bf16x8 afr[4], bfr[4];
#pragma unroll
    for (int mf = 0; mf < 4; ++mf) {
      int m = wmi * 64 + mf * 16 + l15;
      afr[mf] = *(const bf16x8*)(Ac + m * 64 + ((g ^ ((m >> 1) & 3)) << 4));
    }
#pragma unroll
    for (int nf = 0; nf < 4; ++nf) {
      int n = wni * 64 + nf * 16 + l15;
      bfr[nf] = *(const bf16x8*)(Bc + n * 64 + ((g ^ ((n >> 1) & 3)) << 4));
    }

    if (t + 3 < nt) STG(t + 3, (t + 3) & 3);

    __builtin_amdgcn_s_setprio(1);
#pragma unroll
    for (int mf = 0; mf < 4; ++mf)
#pragma unroll
      for (int nf = 0; nf < 4; ++nf)
        acc[mf][nf] = MFMA(afr[mf], bfr[nf], acc[mf][nf]);
    __builtin_amdgcn_s_setprio(0);

    if (t + 3 < nt)      asm volatile("s_waitcnt vmcnt(4)" ::: "memory");
    else if (t + 2 < nt) asm volatile("s_waitcnt vmcnt(2)" ::: "memory");
    else                 asm volatile("s_waitcnt vmcnt(0)" ::: "memory");
    __builtin_amdgcn_s_barrier();
    asm volatile("" ::: "memory");
  }
#undef STG

#pragma unroll
  for (int mf = 0; mf < 4; ++mf)
#pragma unroll
    for (int r = 0; r < 4; ++r) {
      int row = bm + wmi * 64 + mf * 16 + g * 4 + r;
      float rb = (BIAS == 1) ? bias[row] : 0.f;
#pragma unroll
      for (int nf = 0; nf < 4; ++nf) {
        int col = bn + wni * 64 + nf * 16 + l15;
        float v = acc[mf][nf][r] + rb + ((BIAS == 2) ? bias[col] : 0.f);
        if (OBF16) ((unsigned short*)Cout)[(size_t)row * ldc + col] = f2b(v);
        else       ((float*)Cout)[(size_t)row * ldc + col] = v;
      }
    }
}

// ---------------------------------------------------------------------------
// xEF split-K GEMM, 128x128 tile, 3-buffer counted pipeline, split=2
// (K=2048 per slice): Cpart[z][512][1024] f32, z = split*4 + b, 8 z-slices.
// ---------------------------------------------------------------------------
__global__ __launch_bounds__(256, 2) void gemm_xef_splitk(
    const unsigned short* __restrict__ A,
    const unsigned short* __restrict__ B,
    float* __restrict__ Cpart) {
  __shared__ unsigned short Asm_[3][128 * 32];
  __shared__ unsigned short Bsm_[3][128 * 32];
  const int tid = threadIdx.x;
  const int wave = tid >> 6, lane = tid & 63;
  const int g = lane >> 4, l15 = lane & 15;
  const int bm = blockIdx.x * 128, bn = blockIdx.y * 128;
  const int z = blockIdx.z, split = z >> 2, b = z & 3;
  const unsigned short* Ab = A + split * 2048;                    // K-offset
  const unsigned short* Bb = B + (size_t)b * 1024 * 4096 + split * 2048;
  const int wm = (wave >> 1) * 64, wn = (wave & 1) * 64;

  const int rr0 = wave * 16 + (lane >> 2);
  const int rr1 = rr0 + 64;
  const int sl0 = (lane & 3) ^ ((rr0 >> 1) & 3);
  const int sl1 = (lane & 3) ^ ((rr1 >> 1) & 3);

#define XEF_STAGE(T, BUF)                                                           \
  {                                                                                 \
    int kt_ = (T) * 32;                                                             \
    gll16(Ab + (size_t)(bm + rr0) * 4096 + kt_ + sl0 * 8, Asm_[BUF] + wave * 512);  \
    gll16(Bb + (size_t)(bn + rr0) * 4096 + kt_ + sl0 * 8, Bsm_[BUF] + wave * 512);  \
    gll16(Ab + (size_t)(bm + rr1) * 4096 + kt_ + sl1 * 8, Asm_[BUF] + (wave + 4) * 512); \
    gll16(Bb + (size_t)(bn + rr1) * 4096 + kt_ + sl1 * 8, Bsm_[BUF] + (wave + 4) * 512); \
  }

  f32x4 acc[4][4];
#pragma unroll
  for (int i = 0; i < 4; ++i)
#pragma unroll
    for (int j = 0; j < 4; ++j) acc[i][j] = (f32x4){0.f, 0.f, 0.f, 0.f};

  const int nt = 64;
  XEF_STAGE(0, 0);
  XEF_STAGE(1, 1);
  asm volatile("s_waitcnt vmcnt(4)" ::: "memory");   // tile0 landed; tile1 in flight
  __builtin_amdgcn_s_barrier();
  asm volatile("" ::: "memory");

  for (int t = 0; t < nt; ++t) {
    const int cur = t % 3;
    const char* Ac = (const char*)Asm_[cur];
    const char* Bc = (const char*)Bsm_[cur];

    bf16x8 af[4], bfr[4];
#pragma unroll
    for (int mi = 0; mi < 4; ++mi) {
      int m = wm + mi * 16 + l15;
      af[mi] = *(const bf16x8*)(Ac + m * 64 + ((g ^ ((m >> 1) & 3)) << 4));
    }
#pragma unroll
    for (int ni = 0; ni < 4; ++ni) {
      int n = wn + ni * 16 + l15;
      bfr[ni] = *(const bf16x8*)(Bc + n * 64 + ((g ^ ((n >> 1) & 3)) << 4));
    }

    if (t + 2 < nt) XEF_STAGE(t + 2, (t + 2) % 3);

#pragma unroll
    for (int mi = 0; mi < 4; ++mi)
#pragma unroll
      for (int ni = 0; ni < 4; ++ni)
        acc[mi][ni] = MFMA(af[mi], bfr[ni], acc[mi][ni]);

    // retire tile t+1's 4 stages (every wave); keep t+2's 4 in flight
    if (t + 2 < nt) asm volatile("s_waitcnt vmcnt(4)" ::: "memory");
    else            asm volatile("s_waitcnt vmcnt(0)" ::: "memory");
    __builtin_amdgcn_s_barrier();
    asm volatile("" ::: "memory");
  }
#undef XEF_STAGE

  float* C = Cpart + (size_t)z * (512 * 1024);
#pragma unroll
  for (int mi = 0; mi < 4; ++mi)
#pragma unroll
    for (int r = 0; r < 4; ++r) {
      int row = bm + wm + mi * 16 + g * 4 + r;
#pragma unroll
      for (int ni = 0; ni < 4; ++ni) {
        int col = bn + wn + ni * 16 + l15;
        C[(size_t)row * 1024 + col] = acc[mi][ni][r];
      }
    }
}

// ---------------------------------------------------------------------------
// Reduce 2 split-K partials -> xEF bf16 [4][512][1024], + EF bias (per row).
// Split-1 partials at float offset 4*512*1024 = 2,097,152. 8 floats/thread.
// ---------------------------------------------------------------------------
__global__ void reduce_xef(const float* __restrict__ P,
                           const float* __restrict__ bias,
                           unsigned short* __restrict__ out) {
  int t = blockIdx.x * 256 + threadIdx.x;     // 0..262143
  size_t flat = (size_t)t * 8;                // over [4][512][1024]
  float4 a0 = *(const float4*)(P + flat);
  float4 a1 = *(const float4*)(P + flat + 4);
  float4 b0 = *(const float4*)(P + (size_t)2097152 + flat);
  float4 b1 = *(const float4*)(P + (size_t)2097152 + flat + 4);
  float rb = bias[(flat >> 10) & 511];
  u16x8 o;
  o[0] = f2b(a0.x + b0.x + rb); o[1] = f2b(a0.y + b0.y + rb);
  o[2] = f2b(a0.z + b0.z + rb); o[3] = f2b(a0.w + b0.w + rb);
  o[4] = f2b(a1.x + b1.x + rb); o[5] = f2b(a1.y + b1.y + rb);
  o[6] = f2b(a1.z + b1.z + rb); o[7] = f2b(a1.w + b1.w + rb);
  *(u16x8*)(out + flat) = o;
}

// ---------------------------------------------------------------------------
// Merged Kp+Vp GEMM: 512 linear blocks of 256 threads, 64x64 tiles, BK=32,
// 3-buffer counted pipeline (R18-proven body). id<256 = Kp job
// (Kp[b][16][256][64] = xE[b]*Wk^T, head-blocked epilogue); else Vp job
// (Vp[b][hd][dk-permuted] = Wv*xF[b]^T, k-bit-swap epilogue). K=1024 both.
// ---------------------------------------------------------------------------
__global__ __launch_bounds__(256, 4) void gemm_kpvp(
    const unsigned short* __restrict__ xEF, const unsigned short* __restrict__ Wkb,
    const unsigned short* __restrict__ Wvb, unsigned short* __restrict__ Kp,
    unsigned short* __restrict__ Vp) {
  __shared__ unsigned short Asm_[3][64 * 32];
  __shared__ unsigned short Bsm_[3][64 * 32];
  const int tid = threadIdx.x;
  const int wave = tid >> 6, lane = tid & 63;
  const int g = lane >> 4, l15 = lane & 15;

  const int id = blockIdx.x;
  const bool isV = id >= 256;
  const int id2 = isV ? id - 256 : id;
  int bm, bn, bz;
  const unsigned short *Ab, *Bb;
  if (!isV) {                       // Kp: grid was (4,16,4)
    bm = (id2 & 3) * 64; bn = ((id2 >> 2) & 15) * 64; bz = id2 >> 6;
    Ab = xEF + (size_t)bz * (512 * 1024);            // xE rows 0..255
    Bb = Wkb;
  } else {                          // Vp: grid was (16,4,4)
    bm = (id2 & 15) * 64; bn = ((id2 >> 4) & 3) * 64; bz = id2 >> 6;
    Ab = Wvb;
    Bb = xEF + (size_t)bz * (512 * 1024) + 256 * 1024;  // xF rows
  }
  const int wm = (wave >> 1) * 32, wn = (wave & 1) * 32;

  const int rr = wave * 16 + (lane >> 2);
  const int sl = (lane & 3) ^ ((rr >> 1) & 3);

#define KV_STAGE(T, BUF)                                                         \
  {                                                                              \
    int kt_ = (T) * 32;                                                          \
    gll16(Ab + (size_t)(bm + rr) * 1024 + kt_ + sl * 8, Asm_[BUF] + wave * 512); \
    gll16(Bb + (size_t)(bn + rr) * 1024 + kt_ + sl * 8, Bsm_[BUF] + wave * 512); \
  }

  f32x4 acc[2][2];
#pragma unroll
  for (int i = 0; i < 2; ++i)
#pragma unroll
    for (int j = 0; j < 2; ++j) acc[i][j] = (f32x4){0.f, 0.f, 0.f, 0.f};

  const int nt = 32;                 // K = 1024
  KV_STAGE(0, 0);
  KV_STAGE(1, 1);
  asm volatile("s_waitcnt vmcnt(2)" ::: "memory");   // tile0 landed; tile1 in flight
  __builtin_amdgcn_s_barrier();
  asm volatile("" ::: "memory");

  for (int t = 0; t < nt; ++t) {
    const int cur = t % 3;
    const char* Ac = (const char*)Asm_[cur];
    const char* Bc = (const char*)Bsm_[cur];

    bf16x8 af[2], bfr[2];
#pragma unroll
    for (int mi = 0; mi < 2; ++mi) {
      int m = wm + mi * 16 + l15;
      af[mi] = *(const bf16x8*)(Ac + m * 64 + ((g ^ ((m >> 1) & 3)) << 4));
    }
#pragma unroll
    for (int ni = 0; ni < 2; ++ni) {
      int n = wn + ni * 16 + l15;
      bfr[ni] = *(const bf16x8*)(Bc + n * 64 + ((g ^ ((n >> 1) & 3)) << 4));
    }

    if (t + 2 < nt) KV_STAGE(t + 2, (t + 2) % 3);

#pragma unroll
    for (int mi = 0; mi < 2; ++mi)
#pragma unroll
      for (int ni = 0; ni < 2; ++ni)
        acc[mi][ni] = MFMA(af[mi], bfr[ni], acc[mi][ni]);

    if (t + 2 < nt) asm volatile("s_waitcnt vmcnt(2)" ::: "memory");
    else            asm volatile("s_waitcnt vmcnt(0)" ::: "memory");
    __builtin_amdgcn_s_barrier();
    asm volatile("" ::: "memory");
  }
#undef KV_STAGE

#pragma unroll
  for (int mi = 0; mi < 2; ++mi)
#pragma unroll
    for (int r = 0; r < 4; ++r) {
      int row = bm + wm + mi * 16 + g * 4 + r;
#pragma unroll
      for (int ni = 0; ni < 2; ++ni) {
        int col = bn + wn + ni * 16 + l15;
        float v = acc[mi][ni][r];
        if (!isV) {
          // head-blocked: Kp[bz] + (col>>6)*(256*64) + row*64 + (col&63)
          unsigned short* C = Kp + (size_t)bz * (256 * 1024);
          C[(size_t)(col >> 6) * 16384 + (size_t)row * 64 + (col & 63)] = f2b(v);
        } else {
          // row-major ldc=256, low-4 col bits permuted (swap bits 2<->3)
          unsigned short* C = Vp + (size_t)bz * (1024 * 256);
          int cl = col & 15;
          int cp = (cl & 3) | ((cl & 4) << 1) | ((cl & 8) >> 1);
          C[(size_t)row * 256 + (col & ~15) + cp] = f2b(v);
        }
      }
    }
}

// ---------------------------------------------------------------------------
// Fused attention v10 per (b, h, 256-row s-block); 8 waves x 32 rows each.
// V staged in LDS once per block (32KB, XOR-swizzled); MFMA row-sum
// denominator; P fully register-resident. (R16-proven, unchanged.)
// ---------------------------------------------------------------------------
__global__ __launch_bounds__(512, 2) void attn_kernel(
    const unsigned short* __restrict__ q,     // [16384, 1024] (Wq pre-scaled)
    const unsigned short* __restrict__ kp,    // [4][16][256][64]
    const unsigned short* __restrict__ vp,    // [4][16][64][256] k-permuted
    unsigned short* __restrict__ ho) {        // [16384, 1024]
  __shared__ unsigned short Ksm[256 * 64];    // [k][d] 128B rows, swizzled
  __shared__ unsigned short Vsm[64 * 256];    // [d][k] 512B rows, slot^(row&7)

  const int tid = threadIdx.x;
  const int wave = tid >> 6, lane = tid & 63;
  const int l31 = lane & 31, hi = lane >> 5;
  const int x = blockIdx.x;                   // 1024 blocks
  const int bh = (x & 7) + ((x >> 7) << 3);   // head id 0..63 (XCD-local)
  const int qq = (x >> 3) & 15;               // s-block 0..15
  const int b = bh >> 4, h = bh & 15;
  const int s0 = qq * 256;

  const unsigned short* kph = kp + (size_t)bh * (256 * 64);
  const unsigned short* vph = vp + (size_t)bh * (64 * 256);

  // stage K [256][64]: 32 chunks of 1KB over 8 waves. chunk c: rows c*8..+7.
  {
    const int r = (lane >> 3), sl = (lane & 7) ^ (lane >> 3);
#pragma unroll
    for (int it = 0; it < 4; ++it) {
      int c = it * 8 + wave;
      gll16(kph + (c * 8 + r) * 64 + sl * 8, Ksm + c * 512);
    }
  }
  // stage V [64][256]: 32 chunks of 1KB (2 rows each) over 8 waves.
  {
    const int rv = lane >> 5;                 // row within chunk
#pragma unroll
    for (int it = 0; it < 4; ++it) {
      int c = it * 8 + wave;
      int row = c * 2 + rv;
      int sl = (lane & 31) ^ (row & 7);
      gll16(vph + (size_t)row * 256 + sl * 8, Vsm + c * 512);
    }
  }

  // Q B-fragments (persistent): lane l31 = s-col, slots = d = dc*16+hi*8+i
  const int srow = s0 + wave * 32 + l31;
  const unsigned short* qrow = q + (size_t)(b * 4096 + srow) * 1024 + h * 64;
  bf16x8 qf[4];
#pragma unroll
  for (int dc = 0; dc < 4; ++dc)
    qf[dc] = *(const bf16x8*)(qrow + dc * 16 + hi * 8);

  bf16x8 ones;
#pragma unroll
  for (int j = 0; j < 8; ++j) ones[j] = (short)0x3F80;   // bf16 1.0

  __syncthreads();   // drains K+V staging

  f32x16 ho0 = {0,0,0,0,0,0,0,0,0,0,0,0,0,0,0,0};
  f32x16 ho1 = {0,0,0,0,0,0,0,0,0,0,0,0,0,0,0,0};
  f32x16 sumacc = {0,0,0,0,0,0,0,0,0,0,0,0,0,0,0,0};

  const int vsw0 = l31 & 7;                   // row swizzle for rows l31, 32+l31
#pragma unroll
  for (int t = 0; t < 8; ++t) {
    bf16x8 vf00 = *(const bf16x8*)((const char*)Vsm + l31 * 512 + (((t * 4 + hi) ^ vsw0) << 4));
    bf16x8 vf01 = *(const bf16x8*)((const char*)Vsm + l31 * 512 + (((t * 4 + 2 + hi) ^ vsw0) << 4));
    bf16x8 vf10 = *(const bf16x8*)((const char*)Vsm + (32 + l31) * 512 + (((t * 4 + hi) ^ vsw0) << 4));
    bf16x8 vf11 = *(const bf16x8*)((const char*)Vsm + (32 + l31) * 512 + (((t * 4 + 2 + hi) ^ vsw0) << 4));

    // QK^T: C[k=32 rows][s=32 cols], contraction d=64 in 4 chunks
    f32x16 qk = {0,0,0,0,0,0,0,0,0,0,0,0,0,0,0,0};
    const int krow = t * 32 + l31;
    const char* kbase = (const char*)Ksm + krow * 128;
#pragma unroll
    for (int dc = 0; dc < 4; ++dc) {
      bf16x8 kf = *(const bf16x8*)(kbase + (((dc * 2 + hi) ^ (l31 & 7)) << 4));
      qk = MFMA32(kf, qf[dc], qk);
    }

    // exp2 (scale baked into Wq) + pack to PV A-frags (no scalar sum)
    uint32_t pk[8];
#pragma unroll
    for (int j = 0; j < 8; ++j) {
      float e0 = exp2f(qk[2 * j]);
      float e1 = exp2f(qk[2 * j + 1]);
      asm("v_cvt_pk_bf16_f32 %0, %1, %2" : "=v"(pk[j]) : "v"(e0), "v"(e1));
    }
    union { uint32_t u[4]; bf16x8 v; } ua, ub;
    ua.u[0] = pk[0]; ua.u[1] = pk[1]; ua.u[2] = pk[2]; ua.u[3] = pk[3];
    ub.u[0] = pk[4]; ub.u[1] = pk[5]; ub.u[2] = pk[6]; ub.u[3] = pk[7];

    ho0 = MFMA32(ua.v, vf00, ho0);
    ho0 = MFMA32(ub.v, vf01, ho0);
    ho1 = MFMA32(ua.v, vf10, ho1);
    ho1 = MFMA32(ub.v, vf11, ho1);
    // denominator: row-sum of P via ones-B MFMA; same C-row layout as ho
    sumacc = MFMA32(ua.v, ones, sumacc);
    sumacc = MFMA32(ub.v, ones, sumacc);
  }

  float rl[16];
#pragma unroll
  for (int reg = 0; reg < 16; ++reg)
    rl[reg] = __builtin_amdgcn_rcpf(sumacc[reg]);

  unsigned short* hob = ho + (size_t)(b * 4096 + s0 + wave * 32) * 1024 + h * 64 + l31;
#pragma unroll
  for (int reg = 0; reg < 16; ++reg) {
    int srw = (reg & 3) + 8 * (reg >> 2) + 4 * hi;
    hob[(size_t)srw * 1024]      = f2b(ho0[reg] * rl[reg]);
    hob[(size_t)srw * 1024 + 32] = f2b(ho1[reg] * rl[reg]);
  }
}

// ---------------------------------------------------------------------------
// Host orchestration
// ---------------------------------------------------------------------------
extern "C" void kernel_launch(void* const* d_in, const int* in_sizes, int n_in,
                              void* d_out, int out_size, void* d_ws, size_t ws_size,
                              hipStream_t stream) {
  (void)in_sizes; (void)n_in; (void)out_size; (void)ws_size;
  const float* x   = (const float*)d_in[0];
  const float* Wq  = (const float*)d_in[1];
  const float* Wk  = (const float*)d_in[2];
  const float* Wv  = (const float*)d_in[3];
  const float* E_w = (const float*)d_in[4];
  const float* E_b = (const float*)d_in[5];
  const float* F_w = (const float*)d_in[6];
  const float* F_b = (const float*)d_in[7];
  const float* Wo  = (const float*)d_in[8];
  const float* bo  = (const float*)d_in[9];
  float* out = (float*)d_out;

  char* ws = (char*)d_ws;
  unsigned short* xb   = (unsigned short*)(ws);               // 33,554,432 (reused as HO)
  unsigned short* xT   = (unsigned short*)(ws + 33554432);    // 33,554,432  [4][1024][4096]
  unsigned short* Qb   = (unsigned short*)(ws + 67108864);    // 33,554,432  [16384][1024]
  unsigned short* Wqb  = (unsigned short*)(ws + 100663296);   //  2,097,152
  unsigned short* Wkb  = (unsigned short*)(ws + 102760448);   //  2,097,152
  unsigned short* Wvb  = (unsigned short*)(ws + 104857600);   //  2,097,152
  unsigned short* Wob  = (unsigned short*)(ws + 106954752);   //  2,097,152
  unsigned short* EFb  = (unsigned short*)(ws + 109051904);   //  4,194,304  [512][4096]
  unsigned short* xEF  = (unsigned short*)(ws + 113246208);   //  4,194,304  [4][512][1024]
  unsigned short* Kp   = (unsigned short*)(ws + 117440512);   //  2,097,152  [4][16][256][64]
  unsigned short* Vp   = (unsigned short*)(ws + 119537664);   //  2,097,152  [4][16][64][256] perm
  float*          EFbias = (float*)(ws + 121634816);          //  2,048      [512]
  float*          Ppart  = (float*)(ws + 121700352);          // 16,777,216  [2][4][512][1024] f32
  unsigned short* HO   = xb;   // xb dead after Q-GEMM

  // merged casts: x -> xb + xT (blocks 0..1023); weights + EFbias (1024..4096)
  cast_all<<<dim3(4097), 256, 0, stream>>>(
      x, xb, xT,
      Wq, Wk, Wv, E_w, F_w, Wo, E_b, F_b,
      Wqb, Wkb, Wvb, EFb, EFb + 2097152 / 2, Wob, EFbias);

  // Q = xb * Wq^T   [16384,1024]   (Wq pre-scaled by log2e/8), 256^2 tiles
  gemm_bt256<0, true><<<dim3(64, 4), 1024, 0, stream>>>(
      xb, Wqb, Qb, nullptr, 1024, 1024, 1024, 1024);

  // xEF split-K (2 slices of K=2048): Ppart[z] = EF * xT[b]^T, z = split*4+b
  gemm_xef_splitk<<<dim3(4, 8, 8), 256, 0, stream>>>(EFb, xT, Ppart);
  // reduce partials + bias -> xEF bf16 [4][512][1024]
  reduce_xef<<<dim3(1024, 1, 1), 256, 0, stream>>>(Ppart, EFbias, xEF);

  // merged Kp + Vp GEMMs (512 linear blocks)
  gemm_kpvp<<<dim3(512), 256, 0, stream>>>(xEF, Wkb, Wvb, Kp, Vp);

  // fused attention -> HO [16384,1024]  (8-wave blocks, 256 rows each)
  attn_kernel<<<dim3(1024, 1, 1), 512, 0, stream>>>(Qb, Kp, Vp, HO);

  // out = HO * Wo^T + bo   (f32), 256^2 tiles, 1024 threads (16 waves)
  gemm_bt256<2, false><<<dim3(64, 4), 1024, 0, stream>>>(
      HO, Wob, out, bo, 1024, 1024, 1024, 1024);
}